// Round 2
// baseline (267.460 us; speedup 1.0000x reference)
//
#include <hip/hip_runtime.h>
#include <math.h>

typedef unsigned int u32;
typedef unsigned long long u64;

#define B 8
#define H 1024
#define W 1536
#define NPIX (H * W)
#define NK 2048
#define BORDER 16
#define NSEG 64
#define TY 8
#define NTILE 6            // W / 256
#define GRIDY 31           // 992 rows / (TY * 4 waves)
#define HBINS 512
#define TOPK_CAP 4096
#define SEG_CAP_MAX 4096
#define CTR_PAD 32
#define IDX_MASK 0x1FFFFFu

// workspace layout (bytes) — [0, OFF_ZERO_END) is zeroed by one memset.
// keys needs no pre-zeroing: rankref_k masks t >= tcount to 0 at load.
#define OFF_TCOUNT 128      // u32[B*CTR_PAD]            ends 1152
#define OFF_HIST   4096     // u32[B*HBINS]              ends 20480
#define OFF_SEGCNT 20480    // u32[B*NSEG*CTR_PAD]       ends 86016
#define OFF_ZERO_END 86016
#define OFF_KEYS   86016    // u64[B*TOPK_CAP]           ends 348160
#define OFF_CAND   348160   // u32[B*NSEG*seg_cap]

__global__ __launch_bounds__(256) void cand_k(const float* __restrict__ neur,
                                              const float* __restrict__ score,
                                              u32* __restrict__ candp,
                                              u32* __restrict__ segcnt,
                                              u32* __restrict__ hist, int seg_cap) {
    __shared__ u32 lh[HBINS];
    int tile = blockIdx.x;
    int b = blockIdx.z;
    int wave = threadIdx.x >> 6;
    int lane = threadIdx.x & 63;
    for (int i = threadIdx.x; i < HBINS; i += 256) lh[i] = 0;
    __syncthreads();

    int strip = blockIdx.y * 4 + wave;
    int y0 = BORDER + strip * TY;
    int x0 = tile * 256 + lane * 4;
    const float* s = score + (size_t)b * NPIX;
    const float* nb = neur + (size_t)b * NPIX;
    bool haveL = (tile > 0) && (lane == 0);
    bool haveR = (tile < NTILE - 1) && (lane == 63);

    // preload: 10 score rows + 8 neur rows, all independent (one vmcnt burst)
    float4 rv[TY + 2];
    float4 nvv[TY];
    float le[TY + 2], re[TY + 2];
    const float* base_row = s + (size_t)(y0 - 1) * W + x0;
    const float* nrow = nb + (size_t)y0 * W + x0;
    #pragma unroll
    for (int r = 0; r < TY + 2; ++r) rv[r] = *(const float4*)(base_row + (size_t)r * W);
    #pragma unroll
    for (int r = 0; r < TY; ++r) nvv[r] = *(const float4*)(nrow + (size_t)r * W);
    #pragma unroll
    for (int r = 0; r < TY + 2; ++r) {
        le[r] = haveL ? base_row[(size_t)r * W - 1] : 0.0f;
        re[r] = haveR ? base_row[(size_t)r * W + 4] : 0.0f;
    }

    bool xok[4];
    #pragma unroll
    for (int e = 0; e < 4; ++e) {
        int x = x0 + e;
        xok[e] = (x >= BORDER) && (x < W - BORDER);
    }

    // phase A: pure register compute of all ext bits
    u32 extbits = 0;
    {
        float4 hm, h0, hp;
        #pragma unroll
        for (int r = 0; r < 2; ++r) {
            float4 c = rv[r];
            float l = __shfl_up(c.w, 1); if (haveL) l = le[r];
            float rr = __shfl_down(c.x, 1); if (haveR) rr = re[r];
            float4 hh;
            hh.x = fmaxf(fmaxf(l, c.x), c.y);
            hh.y = fmaxf(fmaxf(c.x, c.y), c.z);
            hh.z = fmaxf(fmaxf(c.y, c.z), c.w);
            hh.w = fmaxf(fmaxf(c.z, c.w), rr);
            if (r == 0) hm = hh; else h0 = hh;
        }
        #pragma unroll
        for (int ys = 0; ys < TY; ++ys) {
            float4 c = rv[ys + 2];
            float l = __shfl_up(c.w, 1); if (haveL) l = le[ys + 2];
            float rr = __shfl_down(c.x, 1); if (haveR) rr = re[ys + 2];
            hp.x = fmaxf(fmaxf(l, c.x), c.y);
            hp.y = fmaxf(fmaxf(c.x, c.y), c.z);
            hp.z = fmaxf(fmaxf(c.y, c.z), c.w);
            hp.w = fmaxf(fmaxf(c.z, c.w), rr);
            float pv[4];
            pv[0] = fmaxf(fmaxf(hm.x, h0.x), hp.x);
            pv[1] = fmaxf(fmaxf(hm.y, h0.y), hp.y);
            pv[2] = fmaxf(fmaxf(hm.z, h0.z), hp.z);
            pv[3] = fmaxf(fmaxf(hm.w, h0.w), hp.w);
            float4 c0 = rv[ys + 1];
            float cv[4] = {c0.x, c0.y, c0.z, c0.w};
            #pragma unroll
            for (int e = 0; e < 4; ++e)
                if (xok[e] && cv[e] >= pv[e]) extbits |= (1u << (ys * 4 + e));
            hm = h0; h0 = hp;
        }
    }

    // phase B: one wave scan + one leader atomic; nv already in registers
    u32 c = (u32)__popc(extbits);
    u32 scan = c;
    #pragma unroll
    for (int off = 1; off < 64; off <<= 1) {
        u32 o = (u32)__shfl_up((int)scan, off, 64);
        if (lane >= off) scan += o;
    }
    u32 excl = scan - c;
    u32 tot = (u32)__shfl((int)scan, 63, 64);
    if (tot) {
        int seg = (strip * NTILE + tile) & (NSEG - 1);
        u32* ctr = &segcnt[(u32)(b * NSEG + seg) * CTR_PAD];
        u32 base = 0;
        if (lane == 63) base = atomicAdd(ctr, scan);
        base = (u32)__shfl((int)base, 63, 64);
        u32 pos0 = base + excl;
        u32 sbase = (u32)(b * NSEG + seg) * (u32)seg_cap;
        u32 idxbase = (u32)(y0 * W + x0);
        #pragma unroll
        for (int k = 0; k < 32; ++k) {
            if (extbits & (1u << k)) {
                const int ro = k >> 2, e = k & 3;
                float4 nq = nvv[ro];
                float raw = (e == 0) ? nq.x : (e == 1) ? nq.y : (e == 2) ? nq.z : nq.w;
                float nv = fmaxf(raw, 0.0f);
                u32 fb = __float_as_uint(nv);
                u32 bin = fb >> 21; if (bin > HBINS - 1) bin = HBINS - 1;
                atomicAdd(&lh[bin], 1u);
                u32 idx = idxbase + (u32)ro * W + (u32)e;
                u32 p = pos0 + (u32)__popc(extbits & ((1u << k) - 1u));
                if ((int)p < seg_cap) candp[sbase + p] = (bin << 21) | idx;
            }
        }
    }
    __syncthreads();
    for (int i = threadIdx.x; i < HBINS; i += 256) {
        u32 v = lh[i];
        if (v) atomicAdd(&hist[(u32)b * HBINS + i], v);
    }
}

__global__ __launch_bounds__(256) void compact_k(const u32* __restrict__ candp,
                                                 const u32* __restrict__ segcnt,
                                                 const u32* __restrict__ hist,
                                                 const float* __restrict__ neur,
                                                 u64* __restrict__ keysout,
                                                 u32* tcount, int seg_cap) {
    __shared__ u32 piv_s;
    int seg = blockIdx.x;
    int b = blockIdx.y;
    int lane = threadIdx.x & 63;
    // wave 0: recompute pivot from hist (512 bins, 8/lane + shfl scan)
    if (threadIdx.x < 64) {
        if (threadIdx.x == 0) piv_s = 0xFFFFFFFFu;
        u32 v[8];
        u32 s8 = 0;
        #pragma unroll
        for (int e = 0; e < 8; ++e) {
            v[e] = hist[(u32)b * HBINS + (u32)threadIdx.x * 8u + e];
            s8 += v[e];
        }
        u32 incl = s8;
        #pragma unroll
        for (int off = 1; off < 64; off <<= 1) {
            u32 o = (u32)__shfl_up((int)incl, off, 64);
            if (lane >= off) incl += o;
        }
        u32 excl = incl - s8;
        if (excl < NK && incl >= NK) {
            u32 cum = excl;
            u32 T = 0;
            #pragma unroll
            for (int e = 0; e < 8; ++e) {
                cum += v[e];
                if (cum >= NK) { T = (u32)threadIdx.x * 8u + e; break; }
            }
            piv_s = (T + 2u) << 21;  // include bins <= T+1 entirely
        }
    }
    __syncthreads();
    u32 piv = piv_s;
    const float* nb = neur + (size_t)b * NPIX;

    u32 cnt = segcnt[(u32)(b * NSEG + seg) * CTR_PAD];
    if ((int)cnt > seg_cap) cnt = (u32)seg_cap;
    u32 base = (u32)(b * NSEG + seg) * (u32)seg_cap;
    u32 iters = (cnt + 255u) / 256u;
    for (u32 it = 0; it < iters; ++it) {
        u32 i = it * 256u + threadIdx.x;
        bool f = false;
        u32 idx = 0;
        if (i < cnt) {
            u32 p = candp[base + i];
            f = (p < piv);
            idx = p & IDX_MASK;
        }
        u64 m = __ballot((int)f);
        if (m) {
            int leader = __ffsll((long long)m) - 1;
            u32 wbase = 0;
            if (lane == leader) wbase = atomicAdd(&tcount[b * CTR_PAD], (u32)__popcll(m));
            wbase = (u32)__shfl((int)wbase, leader, 64);
            if (f) {
                u32 pos = wbase + (u32)__popcll(m & ((1ull << (u32)lane) - 1ull));
                if (pos < TOPK_CAP) {
                    float nv = fmaxf(nb[idx], 0.0f);
                    float ness = (float)exp(-(double)nv);  // correctly-rounded f32 exp
                    keysout[(u32)b * TOPK_CAP + pos] =
                        ((u64)__float_as_uint(ness) << 32) | (u32)(~idx);
                }
            }
        }
    }
}

// fused exact-rank + Taylor refine, register-ballot form (no LDS!).
// Each wave loads ALL 4096 keys of the batch into registers (chunk c ->
// lane holds key c*64+lane; 128 VGPRs), masked to 0 past tcount. Rank of
// i = sum over chunks of popc(ballot(kj > ki)), with ki broadcast via
// v_readlane (scalar pipe). One wave64 v_cmp_u64 covers 64 compares, so
// the 4096^2 compare matrix costs 4096 VALU cmps/wave instead of 4096
// serialized LDS broadcast reads/wave (the round-1 bottleneck: single
// LDS pipe/CU at ~4 waves/CU == 40+ us).
// Keys distinct; valid keys > 0; pad zeros rank = cnt >= NK (pivot
// guarantees cnt >= NK) so never selected -- same semantics as before.
__global__ __launch_bounds__(256, 1) void rankref_k(const float* __restrict__ neur,
                                                    const float* __restrict__ score,
                                                    const u64* __restrict__ keys,
                                                    const u32* __restrict__ tcount,
                                                    float* __restrict__ out) {
    int b = blockIdx.y;
    int lane = threadIdx.x & 63;
    u32 cnt = tcount[(u32)b * CTR_PAD];
    if (cnt > TOPK_CAP) cnt = TOPK_CAP;
    const u64* kb = keys + (u32)b * TOPK_CAP;

    // all 4096 keys into registers; coalesced dwordx2 bursts, L1/L2-hit
    u64 kj[64];
    #pragma unroll
    for (int c = 0; c < 64; ++c) {
        u32 t = (u32)c * 64u + (u32)lane;
        u64 k = kb[t];
        kj[c] = (t < cnt) ? k : 0ull;
    }
    // this thread's own key (i index)
    u32 iglob = blockIdx.x * 256u + threadIdx.x;
    u64 kown = (iglob < cnt) ? kb[iglob] : 0ull;
    u32 klo_own = (u32)kown;
    u32 khi_own = (u32)(kown >> 32);

    u32 myrank = 0xFFFFFFFFu;
    for (int i = 0; i < 64; ++i) {
        u32 klo = (u32)__builtin_amdgcn_readlane((int)klo_own, i);
        u32 khi = (u32)__builtin_amdgcn_readlane((int)khi_own, i);
        u64 ki = ((u64)khi << 32) | (u64)klo;
        u32 tot = 0;
        #pragma unroll
        for (int c = 0; c < 64; ++c)
            tot += (u32)__popcll(__ballot(kj[c] > ki));
        if (lane == i) myrank = tot;
    }

    if (iglob >= cnt || myrank >= NK) return;

    u32 idx = ~(u32)kown;
    if (idx >= (u32)NPIX) return;  // defensive: never true for legitimate keys
    const float* s = score + (size_t)b * NPIX;
    const float* nb = neur + (size_t)b * NPIX;
    int y = (int)(idx / W), x = (int)(idx % W);
    int yc = min(max(y, 1), H - 2), xc = min(max(x, 1), W - 2);
    int p = yc * W + xc;
    float s00 = s[p], sp0 = s[p + W], sm0 = s[p - W], s0p = s[p + 1], s0m = s[p - 1];
    float spp = s[p + W + 1], spm = s[p + W - 1], smp = s[p - W + 1], smm = s[p - W - 1];
    float gy = 0.5f * (sp0 - sm0);
    float gx = 0.5f * (s0p - s0m);
    float hyy = sp0 - 2.0f * s00 + sm0;
    float hxx = s0p - 2.0f * s00 + s0m;
    float hxy = 0.25f * (spp - spm - smp + smm);
    float det = hyy * hxx - hxy * hxy;
    bool sing = fabsf(det) > 1e-12f;
    float sd = sing ? det : 1.0f;
    float iy = -(hxx * gy - hxy * gx) / sd;
    float ix = -(hyy * gx - hxy * gy) / sd;
    if (!sing) { iy = 0.0f; ix = 0.0f; }
    iy = fminf(fmaxf(iy, -0.5f), 0.5f);
    ix = fminf(fmaxf(ix, -0.5f), 0.5f);
    size_t o = ((size_t)b * NK + (size_t)myrank) * 3;
    out[o] = (float)y + 0.5f + iy;
    out[o + 1] = (float)x + 0.5f + ix;
    out[o + 2] = fmaxf(nb[idx], 0.0f);
}

extern "C" void kernel_launch(void* const* d_in, const int* in_sizes, int n_in,
                              void* d_out, int out_size, void* d_ws, size_t ws_size,
                              hipStream_t stream) {
    const float* neur = (const float*)d_in[0];
    const float* score = (const float*)d_in[1];
    float* out = (float*)d_out;
    char* ws = (char*)d_ws;
    u32* tcount = (u32*)(ws + OFF_TCOUNT);
    u32* hist = (u32*)(ws + OFF_HIST);
    u32* segcnt = (u32*)(ws + OFF_SEGCNT);
    u64* keysbuf = (u64*)(ws + OFF_KEYS);
    u32* candp = (u32*)(ws + OFF_CAND);

    size_t avail = ws_size > OFF_CAND ? ws_size - OFF_CAND : 0;
    long long cap_ll = (long long)(avail / (4ull * B * NSEG));
    int seg_cap = cap_ll > SEG_CAP_MAX ? SEG_CAP_MAX : (int)cap_ll;

    // zero tcount/hist/segcnt in one memset node (keys masked at load, not zeroed)
    hipMemsetAsync(ws, 0, OFF_ZERO_END, stream);
    cand_k<<<dim3(NTILE, GRIDY, B), 256, 0, stream>>>(neur, score, candp, segcnt, hist, seg_cap);
    compact_k<<<dim3(NSEG, B), 256, 0, stream>>>(candp, segcnt, hist, neur, keysbuf, tcount, seg_cap);
    rankref_k<<<dim3(TOPK_CAP / 256, B), 256, 0, stream>>>(neur, score, keysbuf, tcount, out);
}

// Round 3
// 257.222 us; speedup vs baseline: 1.0398x; 1.0398x over previous
//
#include <hip/hip_runtime.h>
#include <math.h>

typedef unsigned int u32;
typedef unsigned long long u64;

#define B 8
#define H 1024
#define W 1536
#define NPIX (H * W)
#define NK 2048
#define BORDER 16
#define NSEG 64
#define TY 8
#define NTILE 6            // W / 256
#define GRIDY 31           // 992 rows / (TY * 4 waves)
#define HBINS 512
#define TOPK_CAP 4096
#define SEG_CAP_MAX 4096
#define CTR_PAD 32
#define IDX_MASK 0x1FFFFFu

// rankref_k j-tiling: JT keys per lane per tile (JT*2 VGPRs), NOUT tiles.
#define JT 16
#define NOUT (TOPK_CAP / (JT * 64))   // 4

// workspace layout (bytes) — [0, OFF_ZERO_END) is zeroed by one memset.
// keys needs no pre-zeroing: rankref_k masks t >= tcount to 0 at load.
#define OFF_TCOUNT 128      // u32[B*CTR_PAD]            ends 1152
#define OFF_HIST   4096     // u32[B*HBINS]              ends 20480
#define OFF_SEGCNT 20480    // u32[B*NSEG*CTR_PAD]       ends 86016
#define OFF_ZERO_END 86016
#define OFF_KEYS   86016    // u64[B*TOPK_CAP]           ends 348160
#define OFF_CAND   348160   // u32[B*NSEG*seg_cap]

__global__ __launch_bounds__(256) void cand_k(const float* __restrict__ neur,
                                              const float* __restrict__ score,
                                              u32* __restrict__ candp,
                                              u32* __restrict__ segcnt,
                                              u32* __restrict__ hist, int seg_cap) {
    __shared__ u32 lh[HBINS];
    int tile = blockIdx.x;
    int b = blockIdx.z;
    int wave = threadIdx.x >> 6;
    int lane = threadIdx.x & 63;
    for (int i = threadIdx.x; i < HBINS; i += 256) lh[i] = 0;
    __syncthreads();

    int strip = blockIdx.y * 4 + wave;
    int y0 = BORDER + strip * TY;
    int x0 = tile * 256 + lane * 4;
    const float* s = score + (size_t)b * NPIX;
    const float* nb = neur + (size_t)b * NPIX;
    bool haveL = (tile > 0) && (lane == 0);
    bool haveR = (tile < NTILE - 1) && (lane == 63);

    // preload: 10 score rows + 8 neur rows, all independent (one vmcnt burst)
    float4 rv[TY + 2];
    float4 nvv[TY];
    float le[TY + 2], re[TY + 2];
    const float* base_row = s + (size_t)(y0 - 1) * W + x0;
    const float* nrow = nb + (size_t)y0 * W + x0;
    #pragma unroll
    for (int r = 0; r < TY + 2; ++r) rv[r] = *(const float4*)(base_row + (size_t)r * W);
    #pragma unroll
    for (int r = 0; r < TY; ++r) nvv[r] = *(const float4*)(nrow + (size_t)r * W);
    #pragma unroll
    for (int r = 0; r < TY + 2; ++r) {
        le[r] = haveL ? base_row[(size_t)r * W - 1] : 0.0f;
        re[r] = haveR ? base_row[(size_t)r * W + 4] : 0.0f;
    }

    bool xok[4];
    #pragma unroll
    for (int e = 0; e < 4; ++e) {
        int x = x0 + e;
        xok[e] = (x >= BORDER) && (x < W - BORDER);
    }

    // phase A: pure register compute of all ext bits
    u32 extbits = 0;
    {
        float4 hm, h0, hp;
        #pragma unroll
        for (int r = 0; r < 2; ++r) {
            float4 c = rv[r];
            float l = __shfl_up(c.w, 1); if (haveL) l = le[r];
            float rr = __shfl_down(c.x, 1); if (haveR) rr = re[r];
            float4 hh;
            hh.x = fmaxf(fmaxf(l, c.x), c.y);
            hh.y = fmaxf(fmaxf(c.x, c.y), c.z);
            hh.z = fmaxf(fmaxf(c.y, c.z), c.w);
            hh.w = fmaxf(fmaxf(c.z, c.w), rr);
            if (r == 0) hm = hh; else h0 = hh;
        }
        #pragma unroll
        for (int ys = 0; ys < TY; ++ys) {
            float4 c = rv[ys + 2];
            float l = __shfl_up(c.w, 1); if (haveL) l = le[ys + 2];
            float rr = __shfl_down(c.x, 1); if (haveR) rr = re[ys + 2];
            hp.x = fmaxf(fmaxf(l, c.x), c.y);
            hp.y = fmaxf(fmaxf(c.x, c.y), c.z);
            hp.z = fmaxf(fmaxf(c.y, c.z), c.w);
            hp.w = fmaxf(fmaxf(c.z, c.w), rr);
            float pv[4];
            pv[0] = fmaxf(fmaxf(hm.x, h0.x), hp.x);
            pv[1] = fmaxf(fmaxf(hm.y, h0.y), hp.y);
            pv[2] = fmaxf(fmaxf(hm.z, h0.z), hp.z);
            pv[3] = fmaxf(fmaxf(hm.w, h0.w), hp.w);
            float4 c0 = rv[ys + 1];
            float cv[4] = {c0.x, c0.y, c0.z, c0.w};
            #pragma unroll
            for (int e = 0; e < 4; ++e)
                if (xok[e] && cv[e] >= pv[e]) extbits |= (1u << (ys * 4 + e));
            hm = h0; h0 = hp;
        }
    }

    // phase B: one wave scan + one leader atomic; nv already in registers
    u32 c = (u32)__popc(extbits);
    u32 scan = c;
    #pragma unroll
    for (int off = 1; off < 64; off <<= 1) {
        u32 o = (u32)__shfl_up((int)scan, off, 64);
        if (lane >= off) scan += o;
    }
    u32 excl = scan - c;
    u32 tot = (u32)__shfl((int)scan, 63, 64);
    if (tot) {
        int seg = (strip * NTILE + tile) & (NSEG - 1);
        u32* ctr = &segcnt[(u32)(b * NSEG + seg) * CTR_PAD];
        u32 base = 0;
        if (lane == 63) base = atomicAdd(ctr, scan);
        base = (u32)__shfl((int)base, 63, 64);
        u32 pos0 = base + excl;
        u32 sbase = (u32)(b * NSEG + seg) * (u32)seg_cap;
        u32 idxbase = (u32)(y0 * W + x0);
        #pragma unroll
        for (int k = 0; k < 32; ++k) {
            if (extbits & (1u << k)) {
                const int ro = k >> 2, e = k & 3;
                float4 nq = nvv[ro];
                float raw = (e == 0) ? nq.x : (e == 1) ? nq.y : (e == 2) ? nq.z : nq.w;
                float nv = fmaxf(raw, 0.0f);
                u32 fb = __float_as_uint(nv);
                u32 bin = fb >> 21; if (bin > HBINS - 1) bin = HBINS - 1;
                atomicAdd(&lh[bin], 1u);
                u32 idx = idxbase + (u32)ro * W + (u32)e;
                u32 p = pos0 + (u32)__popc(extbits & ((1u << k) - 1u));
                if ((int)p < seg_cap) candp[sbase + p] = (bin << 21) | idx;
            }
        }
    }
    __syncthreads();
    for (int i = threadIdx.x; i < HBINS; i += 256) {
        u32 v = lh[i];
        if (v) atomicAdd(&hist[(u32)b * HBINS + i], v);
    }
}

__global__ __launch_bounds__(256) void compact_k(const u32* __restrict__ candp,
                                                 const u32* __restrict__ segcnt,
                                                 const u32* __restrict__ hist,
                                                 const float* __restrict__ neur,
                                                 u64* __restrict__ keysout,
                                                 u32* tcount, int seg_cap) {
    __shared__ u32 piv_s;
    int seg = blockIdx.x;
    int b = blockIdx.y;
    int lane = threadIdx.x & 63;
    // wave 0: recompute pivot from hist (512 bins, 8/lane + shfl scan)
    if (threadIdx.x < 64) {
        if (threadIdx.x == 0) piv_s = 0xFFFFFFFFu;
        u32 v[8];
        u32 s8 = 0;
        #pragma unroll
        for (int e = 0; e < 8; ++e) {
            v[e] = hist[(u32)b * HBINS + (u32)threadIdx.x * 8u + e];
            s8 += v[e];
        }
        u32 incl = s8;
        #pragma unroll
        for (int off = 1; off < 64; off <<= 1) {
            u32 o = (u32)__shfl_up((int)incl, off, 64);
            if (lane >= off) incl += o;
        }
        u32 excl = incl - s8;
        if (excl < NK && incl >= NK) {
            u32 cum = excl;
            u32 T = 0;
            #pragma unroll
            for (int e = 0; e < 8; ++e) {
                cum += v[e];
                if (cum >= NK) { T = (u32)threadIdx.x * 8u + e; break; }
            }
            piv_s = (T + 2u) << 21;  // include bins <= T+1 entirely
        }
    }
    __syncthreads();
    u32 piv = piv_s;
    const float* nb = neur + (size_t)b * NPIX;

    u32 cnt = segcnt[(u32)(b * NSEG + seg) * CTR_PAD];
    if ((int)cnt > seg_cap) cnt = (u32)seg_cap;
    u32 base = (u32)(b * NSEG + seg) * (u32)seg_cap;
    u32 iters = (cnt + 255u) / 256u;
    for (u32 it = 0; it < iters; ++it) {
        u32 i = it * 256u + threadIdx.x;
        bool f = false;
        u32 idx = 0;
        if (i < cnt) {
            u32 p = candp[base + i];
            f = (p < piv);
            idx = p & IDX_MASK;
        }
        u64 m = __ballot((int)f);
        if (m) {
            int leader = __ffsll((long long)m) - 1;
            u32 wbase = 0;
            if (lane == leader) wbase = atomicAdd(&tcount[b * CTR_PAD], (u32)__popcll(m));
            wbase = (u32)__shfl((int)wbase, leader, 64);
            if (f) {
                u32 pos = wbase + (u32)__popcll(m & ((1ull << (u32)lane) - 1ull));
                if (pos < TOPK_CAP) {
                    float nv = fmaxf(nb[idx], 0.0f);
                    float ness = (float)exp(-(double)nv);  // correctly-rounded f32 exp
                    keysout[(u32)b * TOPK_CAP + pos] =
                        ((u64)__float_as_uint(ness) << 32) | (u32)(~idx);
                }
            }
        }
    }
}

// fused exact-rank + Taylor refine, j-TILED register-ballot form.
// Round-2 failure: kj[64] (128 VGPRs) spilled to scratch (VGPR_Count=100),
// turning the rank loop into 32 KB/thread of serialized scratch reads
// (117 us). Fix: tile j — each wave holds only JT=16 keys (32 VGPRs,
// un-spillable) and loops NOUT=4 tiles of {coalesced L2 chunk load ->
// 64 readlane-broadcast own-keys -> JT ballots each}. Same 4096
// v_cmp_gt_u64 per wave (~2-4 cyc, s_bcnt1 dual-issues on scalar pipe)
// ~= 5-7 us. 128-thread blocks x 32/batch = 256 blocks = 1/CU, 2 waves
// on separate SIMDs.
// Rank semantics bit-identical: rank[i] = #{j : key_j > key_i}; keys
// distinct; pads (t >= tcount) masked to 0, contribute 0, own-pad lanes
// return before output. cnt >= NK by pivot construction.
__global__ __launch_bounds__(128, 1) void rankref_k(const float* __restrict__ neur,
                                                    const float* __restrict__ score,
                                                    const u64* __restrict__ keys,
                                                    const u32* __restrict__ tcount,
                                                    float* __restrict__ out) {
    int b = blockIdx.y;
    int lane = threadIdx.x & 63;
    u32 cnt = tcount[(u32)b * CTR_PAD];
    if (cnt > TOPK_CAP) cnt = TOPK_CAP;
    const u64* kb = keys + (u32)b * TOPK_CAP;

    // this thread's own key (i index)
    u32 iglob = blockIdx.x * 128u + threadIdx.x;
    u64 kown = (iglob < cnt) ? kb[iglob] : 0ull;
    u32 klo_own = (u32)kown;
    u32 khi_own = (u32)(kown >> 32);

    u32 myrank = 0;
    for (int oc = 0; oc < NOUT; ++oc) {
        // load this tile's JT j-chunks: lane holds key (oc*JT+c)*64 + lane
        u64 kj[JT];
        #pragma unroll
        for (int c = 0; c < JT; ++c) {
            u32 t = (u32)(oc * JT + c) * 64u + (u32)lane;
            u64 k = kb[t];
            kj[c] = (t < cnt) ? k : 0ull;
        }
        // for each of the wave's 64 own-keys: broadcast, ballot-count
        for (int i = 0; i < 64; ++i) {
            u32 klo = (u32)__builtin_amdgcn_readlane((int)klo_own, i);
            u32 khi = (u32)__builtin_amdgcn_readlane((int)khi_own, i);
            u64 ki = ((u64)khi << 32) | (u64)klo;
            u32 tot = 0;
            #pragma unroll
            for (int c = 0; c < JT; ++c)
                tot += (u32)__popcll(__ballot(kj[c] > ki));
            if (lane == i) myrank += tot;
        }
    }

    if (iglob >= cnt || myrank >= NK) return;

    u32 idx = ~(u32)kown;
    if (idx >= (u32)NPIX) return;  // defensive: never true for legitimate keys
    const float* s = score + (size_t)b * NPIX;
    const float* nb = neur + (size_t)b * NPIX;
    int y = (int)(idx / W), x = (int)(idx % W);
    int yc = min(max(y, 1), H - 2), xc = min(max(x, 1), W - 2);
    int p = yc * W + xc;
    float s00 = s[p], sp0 = s[p + W], sm0 = s[p - W], s0p = s[p + 1], s0m = s[p - 1];
    float spp = s[p + W + 1], spm = s[p + W - 1], smp = s[p - W + 1], smm = s[p - W - 1];
    float gy = 0.5f * (sp0 - sm0);
    float gx = 0.5f * (s0p - s0m);
    float hyy = sp0 - 2.0f * s00 + sm0;
    float hxx = s0p - 2.0f * s00 + s0m;
    float hxy = 0.25f * (spp - spm - smp + smm);
    float det = hyy * hxx - hxy * hxy;
    bool sing = fabsf(det) > 1e-12f;
    float sd = sing ? det : 1.0f;
    float iy = -(hxx * gy - hxy * gx) / sd;
    float ix = -(hyy * gx - hxy * gy) / sd;
    if (!sing) { iy = 0.0f; ix = 0.0f; }
    iy = fminf(fmaxf(iy, -0.5f), 0.5f);
    ix = fminf(fmaxf(ix, -0.5f), 0.5f);
    size_t o = ((size_t)b * NK + (size_t)myrank) * 3;
    out[o] = (float)y + 0.5f + iy;
    out[o + 1] = (float)x + 0.5f + ix;
    out[o + 2] = fmaxf(nb[idx], 0.0f);
}

extern "C" void kernel_launch(void* const* d_in, const int* in_sizes, int n_in,
                              void* d_out, int out_size, void* d_ws, size_t ws_size,
                              hipStream_t stream) {
    const float* neur = (const float*)d_in[0];
    const float* score = (const float*)d_in[1];
    float* out = (float*)d_out;
    char* ws = (char*)d_ws;
    u32* tcount = (u32*)(ws + OFF_TCOUNT);
    u32* hist = (u32*)(ws + OFF_HIST);
    u32* segcnt = (u32*)(ws + OFF_SEGCNT);
    u64* keysbuf = (u64*)(ws + OFF_KEYS);
    u32* candp = (u32*)(ws + OFF_CAND);

    size_t avail = ws_size > OFF_CAND ? ws_size - OFF_CAND : 0;
    long long cap_ll = (long long)(avail / (4ull * B * NSEG));
    int seg_cap = cap_ll > SEG_CAP_MAX ? SEG_CAP_MAX : (int)cap_ll;

    // zero tcount/hist/segcnt in one memset node (keys masked at load, not zeroed)
    hipMemsetAsync(ws, 0, OFF_ZERO_END, stream);
    cand_k<<<dim3(NTILE, GRIDY, B), 256, 0, stream>>>(neur, score, candp, segcnt, hist, seg_cap);
    compact_k<<<dim3(NSEG, B), 256, 0, stream>>>(candp, segcnt, hist, neur, keysbuf, tcount, seg_cap);
    rankref_k<<<dim3(TOPK_CAP / 128, B), 128, 0, stream>>>(neur, score, keysbuf, tcount, out);
}

// Round 4
// 186.180 us; speedup vs baseline: 1.4366x; 1.3816x over previous
//
#include <hip/hip_runtime.h>
#include <math.h>

typedef unsigned int u32;
typedef unsigned long long u64;

#define B 8
#define H 1024
#define W 1536
#define NPIX (H * W)
#define NK 2048
#define BORDER 16
#define NSEG 64
#define TY 8
#define NTILE 6            // W / 256
#define GRIDY 31           // 992 rows / (TY * 4 waves)
#define HBINS 512
#define TOPK_CAP 4096
#define SEG_CAP_MAX 4096
#define CTR_PAD 32
#define IDX_MASK 0x1FFFFFu

// workspace layout (bytes) — [0, OFF_ZERO_END) is zeroed by one memset.
// keys needs no pre-zeroing: rankref_k clips j to tcount at compare time.
#define OFF_TCOUNT 128      // u32[B*CTR_PAD]            ends 1152
#define OFF_HIST   4096     // u32[B*HBINS]              ends 20480
#define OFF_SEGCNT 20480    // u32[B*NSEG*CTR_PAD]       ends 86016
#define OFF_ZERO_END 86016
#define OFF_KEYS   86016    // u64[B*TOPK_CAP]           ends 348160
#define OFF_CAND   348160   // u32[B*NSEG*seg_cap]

__global__ __launch_bounds__(256) void cand_k(const float* __restrict__ neur,
                                              const float* __restrict__ score,
                                              u32* __restrict__ candp,
                                              u32* __restrict__ segcnt,
                                              u32* __restrict__ hist, int seg_cap) {
    __shared__ u32 lh[HBINS];
    int tile = blockIdx.x;
    int b = blockIdx.z;
    int wave = threadIdx.x >> 6;
    int lane = threadIdx.x & 63;
    for (int i = threadIdx.x; i < HBINS; i += 256) lh[i] = 0;
    __syncthreads();

    int strip = blockIdx.y * 4 + wave;
    int y0 = BORDER + strip * TY;
    int x0 = tile * 256 + lane * 4;
    const float* s = score + (size_t)b * NPIX;
    const float* nb = neur + (size_t)b * NPIX;
    bool haveL = (tile > 0) && (lane == 0);
    bool haveR = (tile < NTILE - 1) && (lane == 63);

    // preload: 10 score rows + 8 neur rows, all independent (one vmcnt burst)
    float4 rv[TY + 2];
    float4 nvv[TY];
    float le[TY + 2], re[TY + 2];
    const float* base_row = s + (size_t)(y0 - 1) * W + x0;
    const float* nrow = nb + (size_t)y0 * W + x0;
    #pragma unroll
    for (int r = 0; r < TY + 2; ++r) rv[r] = *(const float4*)(base_row + (size_t)r * W);
    #pragma unroll
    for (int r = 0; r < TY; ++r) nvv[r] = *(const float4*)(nrow + (size_t)r * W);
    #pragma unroll
    for (int r = 0; r < TY + 2; ++r) {
        le[r] = haveL ? base_row[(size_t)r * W - 1] : 0.0f;
        re[r] = haveR ? base_row[(size_t)r * W + 4] : 0.0f;
    }

    bool xok[4];
    #pragma unroll
    for (int e = 0; e < 4; ++e) {
        int x = x0 + e;
        xok[e] = (x >= BORDER) && (x < W - BORDER);
    }

    // phase A: pure register compute of all ext bits
    u32 extbits = 0;
    {
        float4 hm, h0, hp;
        #pragma unroll
        for (int r = 0; r < 2; ++r) {
            float4 c = rv[r];
            float l = __shfl_up(c.w, 1); if (haveL) l = le[r];
            float rr = __shfl_down(c.x, 1); if (haveR) rr = re[r];
            float4 hh;
            hh.x = fmaxf(fmaxf(l, c.x), c.y);
            hh.y = fmaxf(fmaxf(c.x, c.y), c.z);
            hh.z = fmaxf(fmaxf(c.y, c.z), c.w);
            hh.w = fmaxf(fmaxf(c.z, c.w), rr);
            if (r == 0) hm = hh; else h0 = hh;
        }
        #pragma unroll
        for (int ys = 0; ys < TY; ++ys) {
            float4 c = rv[ys + 2];
            float l = __shfl_up(c.w, 1); if (haveL) l = le[ys + 2];
            float rr = __shfl_down(c.x, 1); if (haveR) rr = re[ys + 2];
            hp.x = fmaxf(fmaxf(l, c.x), c.y);
            hp.y = fmaxf(fmaxf(c.x, c.y), c.z);
            hp.z = fmaxf(fmaxf(c.y, c.z), c.w);
            hp.w = fmaxf(fmaxf(c.z, c.w), rr);
            float pv[4];
            pv[0] = fmaxf(fmaxf(hm.x, h0.x), hp.x);
            pv[1] = fmaxf(fmaxf(hm.y, h0.y), hp.y);
            pv[2] = fmaxf(fmaxf(hm.z, h0.z), hp.z);
            pv[3] = fmaxf(fmaxf(hm.w, h0.w), hp.w);
            float4 c0 = rv[ys + 1];
            float cv[4] = {c0.x, c0.y, c0.z, c0.w};
            #pragma unroll
            for (int e = 0; e < 4; ++e)
                if (xok[e] && cv[e] >= pv[e]) extbits |= (1u << (ys * 4 + e));
            hm = h0; h0 = hp;
        }
    }

    // phase B: one wave scan + one leader atomic; nv already in registers
    u32 c = (u32)__popc(extbits);
    u32 scan = c;
    #pragma unroll
    for (int off = 1; off < 64; off <<= 1) {
        u32 o = (u32)__shfl_up((int)scan, off, 64);
        if (lane >= off) scan += o;
    }
    u32 excl = scan - c;
    u32 tot = (u32)__shfl((int)scan, 63, 64);
    if (tot) {
        int seg = (strip * NTILE + tile) & (NSEG - 1);
        u32* ctr = &segcnt[(u32)(b * NSEG + seg) * CTR_PAD];
        u32 base = 0;
        if (lane == 63) base = atomicAdd(ctr, scan);
        base = (u32)__shfl((int)base, 63, 64);
        u32 pos0 = base + excl;
        u32 sbase = (u32)(b * NSEG + seg) * (u32)seg_cap;
        u32 idxbase = (u32)(y0 * W + x0);
        #pragma unroll
        for (int k = 0; k < 32; ++k) {
            if (extbits & (1u << k)) {
                const int ro = k >> 2, e = k & 3;
                float4 nq = nvv[ro];
                float raw = (e == 0) ? nq.x : (e == 1) ? nq.y : (e == 2) ? nq.z : nq.w;
                float nv = fmaxf(raw, 0.0f);
                u32 fb = __float_as_uint(nv);
                u32 bin = fb >> 21; if (bin > HBINS - 1) bin = HBINS - 1;
                atomicAdd(&lh[bin], 1u);
                u32 idx = idxbase + (u32)ro * W + (u32)e;
                u32 p = pos0 + (u32)__popc(extbits & ((1u << k) - 1u));
                if ((int)p < seg_cap) candp[sbase + p] = (bin << 21) | idx;
            }
        }
    }
    __syncthreads();
    for (int i = threadIdx.x; i < HBINS; i += 256) {
        u32 v = lh[i];
        if (v) atomicAdd(&hist[(u32)b * HBINS + i], v);
    }
}

__global__ __launch_bounds__(256) void compact_k(const u32* __restrict__ candp,
                                                 const u32* __restrict__ segcnt,
                                                 const u32* __restrict__ hist,
                                                 const float* __restrict__ neur,
                                                 u64* __restrict__ keysout,
                                                 u32* tcount, int seg_cap) {
    __shared__ u32 piv_s;
    int seg = blockIdx.x;
    int b = blockIdx.y;
    int lane = threadIdx.x & 63;
    // wave 0: recompute pivot from hist (512 bins, 8/lane + shfl scan)
    if (threadIdx.x < 64) {
        if (threadIdx.x == 0) piv_s = 0xFFFFFFFFu;
        u32 v[8];
        u32 s8 = 0;
        #pragma unroll
        for (int e = 0; e < 8; ++e) {
            v[e] = hist[(u32)b * HBINS + (u32)threadIdx.x * 8u + e];
            s8 += v[e];
        }
        u32 incl = s8;
        #pragma unroll
        for (int off = 1; off < 64; off <<= 1) {
            u32 o = (u32)__shfl_up((int)incl, off, 64);
            if (lane >= off) incl += o;
        }
        u32 excl = incl - s8;
        if (excl < NK && incl >= NK) {
            u32 cum = excl;
            u32 T = 0;
            #pragma unroll
            for (int e = 0; e < 8; ++e) {
                cum += v[e];
                if (cum >= NK) { T = (u32)threadIdx.x * 8u + e; break; }
            }
            piv_s = (T + 2u) << 21;  // include bins <= T+1 entirely
        }
    }
    __syncthreads();
    u32 piv = piv_s;
    const float* nb = neur + (size_t)b * NPIX;

    u32 cnt = segcnt[(u32)(b * NSEG + seg) * CTR_PAD];
    if ((int)cnt > seg_cap) cnt = (u32)seg_cap;
    u32 base = (u32)(b * NSEG + seg) * (u32)seg_cap;
    u32 iters = (cnt + 255u) / 256u;
    for (u32 it = 0; it < iters; ++it) {
        u32 i = it * 256u + threadIdx.x;
        bool f = false;
        u32 idx = 0;
        if (i < cnt) {
            u32 p = candp[base + i];
            f = (p < piv);
            idx = p & IDX_MASK;
        }
        u64 m = __ballot((int)f);
        if (m) {
            int leader = __ffsll((long long)m) - 1;
            u32 wbase = 0;
            if (lane == leader) wbase = atomicAdd(&tcount[b * CTR_PAD], (u32)__popcll(m));
            wbase = (u32)__shfl((int)wbase, leader, 64);
            if (f) {
                u32 pos = wbase + (u32)__popcll(m & ((1ull << (u32)lane) - 1ull));
                if (pos < TOPK_CAP) {
                    float nv = fmaxf(nb[idx], 0.0f);
                    float ness = (float)exp(-(double)nv);  // correctly-rounded f32 exp
                    keysout[(u32)b * TOPK_CAP + pos] =
                        ((u64)__float_as_uint(ness) << 32) | (u32)(~idx);
                }
            }
        }
    }
}

// fused exact-rank + Taylor refine, scalar-broadcast form.
// Round-3 failure: ballot-rank's v_cmp -> vcc -> s_bcnt1 is a VALU->SALU
// cross-pipe dependency every iteration (~60 cyc each with 0.5 waves/SIMD;
// VALUBusy 10%). Invert the layout: each LANE owns one i-key in VGPRs,
// the j-key is WAVE-UNIFORM and comes in on the SCALAR pipe
// (s_load_dwordx8 batches from the L2-resident 32 KB key array). Inner
// body per j: v_cmp_gt_u64 (s-pair vs v-pair) + v_addc -- pure VALU,
// vcc forwarded, 64 compares per pair, no cross-lane ops, no LDS.
// j is split over the block's 4 waves (<=1024 each, clipped to cnt so
// garbage past tcount never counted == pads contribute 0, identical
// semantics); partials combined via 768 B LDS; wave 0 refines inline.
// Grid 64 x B = 512 blocks = 2 blocks/CU on all 256 CUs (8 waves/CU).
// rank[i] = #{j : key_j > key_i}; keys distinct; valid keys > 0, so
// pad own-keys (kown=0) get rank = cnt >= NK -> never output.
__global__ __launch_bounds__(256, 1) void rankref_k(const float* __restrict__ neur,
                                                    const float* __restrict__ score,
                                                    const u64* __restrict__ keys,
                                                    const u32* __restrict__ tcount,
                                                    float* __restrict__ out) {
    __shared__ u32 part[3][64];
    int b = blockIdx.y;
    int wave = threadIdx.x >> 6;
    int lane = threadIdx.x & 63;
    u32 cnt = tcount[(u32)b * CTR_PAD];
    if (cnt > TOPK_CAP) cnt = TOPK_CAP;
    const u64* kb = keys + (u32)b * TOPK_CAP;

    // lane's own i-key (same 64 i-keys for all 4 waves of the block)
    u32 i = blockIdx.x * 64u + (u32)lane;
    u64 kown = (i < cnt) ? kb[i] : 0ull;

    // this wave's j-range, clipped to cnt
    int rem = (int)cnt - wave * 1024;
    u32 nj = rem <= 0 ? 0u : (rem > 1024 ? 1024u : (u32)rem);
    const u64* kq = kb + (u32)wave * 1024u;

    u32 myrank = 0;
    u32 nj8 = nj & ~7u;
    for (u32 j = 0; j < nj8; j += 8u) {
        #pragma unroll
        for (int e = 0; e < 8; ++e) {
            u64 ki = kq[j + (u32)e];          // wave-uniform -> scalar load
            myrank += (ki > kown) ? 1u : 0u;  // v_cmp_gt_u64 + v_addc
        }
    }
    for (u32 j = nj8; j < nj; ++j) {
        u64 ki = kq[j];
        myrank += (ki > kown) ? 1u : 0u;
    }

    if (wave) part[wave - 1][lane] = myrank;
    __syncthreads();
    if (wave) return;
    myrank += part[0][lane] + part[1][lane] + part[2][lane];

    if (i >= cnt || myrank >= NK) return;

    u32 idx = ~(u32)kown;
    if (idx >= (u32)NPIX) return;  // defensive: never true for legitimate keys
    const float* s = score + (size_t)b * NPIX;
    const float* nb = neur + (size_t)b * NPIX;
    int y = (int)(idx / W), x = (int)(idx % W);
    int yc = min(max(y, 1), H - 2), xc = min(max(x, 1), W - 2);
    int p = yc * W + xc;
    float s00 = s[p], sp0 = s[p + W], sm0 = s[p - W], s0p = s[p + 1], s0m = s[p - 1];
    float spp = s[p + W + 1], spm = s[p + W - 1], smp = s[p - W + 1], smm = s[p - W - 1];
    float gy = 0.5f * (sp0 - sm0);
    float gx = 0.5f * (s0p - s0m);
    float hyy = sp0 - 2.0f * s00 + sm0;
    float hxx = s0p - 2.0f * s00 + s0m;
    float hxy = 0.25f * (spp - spm - smp + smm);
    float det = hyy * hxx - hxy * hxy;
    bool sing = fabsf(det) > 1e-12f;
    float sd = sing ? det : 1.0f;
    float iy = -(hxx * gy - hxy * gx) / sd;
    float ix = -(hyy * gx - hxy * gy) / sd;
    if (!sing) { iy = 0.0f; ix = 0.0f; }
    iy = fminf(fmaxf(iy, -0.5f), 0.5f);
    ix = fminf(fmaxf(ix, -0.5f), 0.5f);
    size_t o = ((size_t)b * NK + (size_t)myrank) * 3;
    out[o] = (float)y + 0.5f + iy;
    out[o + 1] = (float)x + 0.5f + ix;
    out[o + 2] = fmaxf(nb[idx], 0.0f);
}

extern "C" void kernel_launch(void* const* d_in, const int* in_sizes, int n_in,
                              void* d_out, int out_size, void* d_ws, size_t ws_size,
                              hipStream_t stream) {
    const float* neur = (const float*)d_in[0];
    const float* score = (const float*)d_in[1];
    float* out = (float*)d_out;
    char* ws = (char*)d_ws;
    u32* tcount = (u32*)(ws + OFF_TCOUNT);
    u32* hist = (u32*)(ws + OFF_HIST);
    u32* segcnt = (u32*)(ws + OFF_SEGCNT);
    u64* keysbuf = (u64*)(ws + OFF_KEYS);
    u32* candp = (u32*)(ws + OFF_CAND);

    size_t avail = ws_size > OFF_CAND ? ws_size - OFF_CAND : 0;
    long long cap_ll = (long long)(avail / (4ull * B * NSEG));
    int seg_cap = cap_ll > SEG_CAP_MAX ? SEG_CAP_MAX : (int)cap_ll;

    // zero tcount/hist/segcnt in one memset node (keys clipped at compare, not zeroed)
    hipMemsetAsync(ws, 0, OFF_ZERO_END, stream);
    cand_k<<<dim3(NTILE, GRIDY, B), 256, 0, stream>>>(neur, score, candp, segcnt, hist, seg_cap);
    compact_k<<<dim3(NSEG, B), 256, 0, stream>>>(candp, segcnt, hist, neur, keysbuf, tcount, seg_cap);
    rankref_k<<<dim3(TOPK_CAP / 64, B), 256, 0, stream>>>(neur, score, keysbuf, tcount, out);
}

// Round 5
// 174.436 us; speedup vs baseline: 1.5333x; 1.0673x over previous
//
#include <hip/hip_runtime.h>
#include <math.h>

typedef unsigned int u32;
typedef unsigned long long u64;

#define B 8
#define H 1024
#define W 1536
#define NPIX (H * W)
#define NK 2048
#define BORDER 16
#define NSEG 64
#define TY 8
#define NTILE 6            // W / 256
#define GRIDY 31           // 992 rows / (TY * 4 waves)
#define HBINS 512
#define TOPK_CAP 4096
#define SEG_CAP_MAX 4096
#define CTR_PAD 32
#define IDX_MASK 0x1FFFFFu

// workspace layout (bytes) — [0, OFF_ZERO_END) is zeroed by one memset.
// keys needs no pre-zeroing: rankref_k masks j >= tcount to 0 at load.
#define OFF_TCOUNT 128      // u32[B*CTR_PAD]            ends 1152
#define OFF_HIST   4096     // u32[B*HBINS]              ends 20480
#define OFF_SEGCNT 20480    // u32[B*NSEG*CTR_PAD]       ends 86016
#define OFF_ZERO_END 86016
#define OFF_KEYS   86016    // u64[B*TOPK_CAP]           ends 348160
#define OFF_CAND   348160   // u32[B*NSEG*seg_cap]

__global__ __launch_bounds__(256) void cand_k(const float* __restrict__ neur,
                                              const float* __restrict__ score,
                                              u32* __restrict__ candp,
                                              u32* __restrict__ segcnt,
                                              u32* __restrict__ hist, int seg_cap) {
    __shared__ u32 lh[HBINS];
    int tile = blockIdx.x;
    int b = blockIdx.z;
    int wave = threadIdx.x >> 6;
    int lane = threadIdx.x & 63;
    for (int i = threadIdx.x; i < HBINS; i += 256) lh[i] = 0;
    __syncthreads();

    int strip = blockIdx.y * 4 + wave;
    int y0 = BORDER + strip * TY;
    int x0 = tile * 256 + lane * 4;
    const float* s = score + (size_t)b * NPIX;
    const float* nb = neur + (size_t)b * NPIX;
    bool haveL = (tile > 0) && (lane == 0);
    bool haveR = (tile < NTILE - 1) && (lane == 63);

    // preload: 10 score rows + 8 neur rows, all independent (one vmcnt burst)
    float4 rv[TY + 2];
    float4 nvv[TY];
    float le[TY + 2], re[TY + 2];
    const float* base_row = s + (size_t)(y0 - 1) * W + x0;
    const float* nrow = nb + (size_t)y0 * W + x0;
    #pragma unroll
    for (int r = 0; r < TY + 2; ++r) rv[r] = *(const float4*)(base_row + (size_t)r * W);
    #pragma unroll
    for (int r = 0; r < TY; ++r) nvv[r] = *(const float4*)(nrow + (size_t)r * W);
    #pragma unroll
    for (int r = 0; r < TY + 2; ++r) {
        le[r] = haveL ? base_row[(size_t)r * W - 1] : 0.0f;
        re[r] = haveR ? base_row[(size_t)r * W + 4] : 0.0f;
    }

    bool xok[4];
    #pragma unroll
    for (int e = 0; e < 4; ++e) {
        int x = x0 + e;
        xok[e] = (x >= BORDER) && (x < W - BORDER);
    }

    // phase A: pure register compute of all ext bits
    u32 extbits = 0;
    {
        float4 hm, h0, hp;
        #pragma unroll
        for (int r = 0; r < 2; ++r) {
            float4 c = rv[r];
            float l = __shfl_up(c.w, 1); if (haveL) l = le[r];
            float rr = __shfl_down(c.x, 1); if (haveR) rr = re[r];
            float4 hh;
            hh.x = fmaxf(fmaxf(l, c.x), c.y);
            hh.y = fmaxf(fmaxf(c.x, c.y), c.z);
            hh.z = fmaxf(fmaxf(c.y, c.z), c.w);
            hh.w = fmaxf(fmaxf(c.z, c.w), rr);
            if (r == 0) hm = hh; else h0 = hh;
        }
        #pragma unroll
        for (int ys = 0; ys < TY; ++ys) {
            float4 c = rv[ys + 2];
            float l = __shfl_up(c.w, 1); if (haveL) l = le[ys + 2];
            float rr = __shfl_down(c.x, 1); if (haveR) rr = re[ys + 2];
            hp.x = fmaxf(fmaxf(l, c.x), c.y);
            hp.y = fmaxf(fmaxf(c.x, c.y), c.z);
            hp.z = fmaxf(fmaxf(c.y, c.z), c.w);
            hp.w = fmaxf(fmaxf(c.z, c.w), rr);
            float pv[4];
            pv[0] = fmaxf(fmaxf(hm.x, h0.x), hp.x);
            pv[1] = fmaxf(fmaxf(hm.y, h0.y), hp.y);
            pv[2] = fmaxf(fmaxf(hm.z, h0.z), hp.z);
            pv[3] = fmaxf(fmaxf(hm.w, h0.w), hp.w);
            float4 c0 = rv[ys + 1];
            float cv[4] = {c0.x, c0.y, c0.z, c0.w};
            #pragma unroll
            for (int e = 0; e < 4; ++e)
                if (xok[e] && cv[e] >= pv[e]) extbits |= (1u << (ys * 4 + e));
            hm = h0; h0 = hp;
        }
    }

    // phase B: one wave scan + one leader atomic; nv already in registers
    u32 c = (u32)__popc(extbits);
    u32 scan = c;
    #pragma unroll
    for (int off = 1; off < 64; off <<= 1) {
        u32 o = (u32)__shfl_up((int)scan, off, 64);
        if (lane >= off) scan += o;
    }
    u32 excl = scan - c;
    u32 tot = (u32)__shfl((int)scan, 63, 64);
    if (tot) {
        int seg = (strip * NTILE + tile) & (NSEG - 1);
        u32* ctr = &segcnt[(u32)(b * NSEG + seg) * CTR_PAD];
        u32 base = 0;
        if (lane == 63) base = atomicAdd(ctr, scan);
        base = (u32)__shfl((int)base, 63, 64);
        u32 pos0 = base + excl;
        u32 sbase = (u32)(b * NSEG + seg) * (u32)seg_cap;
        u32 idxbase = (u32)(y0 * W + x0);
        #pragma unroll
        for (int k = 0; k < 32; ++k) {
            if (extbits & (1u << k)) {
                const int ro = k >> 2, e = k & 3;
                float4 nq = nvv[ro];
                float raw = (e == 0) ? nq.x : (e == 1) ? nq.y : (e == 2) ? nq.z : nq.w;
                float nv = fmaxf(raw, 0.0f);
                u32 fb = __float_as_uint(nv);
                u32 bin = fb >> 21; if (bin > HBINS - 1) bin = HBINS - 1;
                atomicAdd(&lh[bin], 1u);
                u32 idx = idxbase + (u32)ro * W + (u32)e;
                u32 p = pos0 + (u32)__popc(extbits & ((1u << k) - 1u));
                if ((int)p < seg_cap) candp[sbase + p] = (bin << 21) | idx;
            }
        }
    }
    __syncthreads();
    for (int i = threadIdx.x; i < HBINS; i += 256) {
        u32 v = lh[i];
        if (v) atomicAdd(&hist[(u32)b * HBINS + i], v);
    }
}

__global__ __launch_bounds__(256) void compact_k(const u32* __restrict__ candp,
                                                 const u32* __restrict__ segcnt,
                                                 const u32* __restrict__ hist,
                                                 const float* __restrict__ neur,
                                                 u64* __restrict__ keysout,
                                                 u32* tcount, int seg_cap) {
    __shared__ u32 piv_s;
    int seg = blockIdx.x;
    int b = blockIdx.y;
    int lane = threadIdx.x & 63;
    // wave 0: recompute pivot from hist (512 bins, 8/lane + shfl scan)
    if (threadIdx.x < 64) {
        if (threadIdx.x == 0) piv_s = 0xFFFFFFFFu;
        u32 v[8];
        u32 s8 = 0;
        #pragma unroll
        for (int e = 0; e < 8; ++e) {
            v[e] = hist[(u32)b * HBINS + (u32)threadIdx.x * 8u + e];
            s8 += v[e];
        }
        u32 incl = s8;
        #pragma unroll
        for (int off = 1; off < 64; off <<= 1) {
            u32 o = (u32)__shfl_up((int)incl, off, 64);
            if (lane >= off) incl += o;
        }
        u32 excl = incl - s8;
        if (excl < NK && incl >= NK) {
            u32 cum = excl;
            u32 T = 0;
            #pragma unroll
            for (int e = 0; e < 8; ++e) {
                cum += v[e];
                if (cum >= NK) { T = (u32)threadIdx.x * 8u + e; break; }
            }
            piv_s = (T + 2u) << 21;  // include bins <= T+1 entirely
        }
    }
    __syncthreads();
    u32 piv = piv_s;
    const float* nb = neur + (size_t)b * NPIX;

    u32 cnt = segcnt[(u32)(b * NSEG + seg) * CTR_PAD];
    if ((int)cnt > seg_cap) cnt = (u32)seg_cap;
    u32 base = (u32)(b * NSEG + seg) * (u32)seg_cap;
    u32 iters = (cnt + 255u) / 256u;
    for (u32 it = 0; it < iters; ++it) {
        u32 i = it * 256u + threadIdx.x;
        bool f = false;
        u32 idx = 0;
        if (i < cnt) {
            u32 p = candp[base + i];
            f = (p < piv);
            idx = p & IDX_MASK;
        }
        u64 m = __ballot((int)f);
        if (m) {
            int leader = __ffsll((long long)m) - 1;
            u32 wbase = 0;
            if (lane == leader) wbase = atomicAdd(&tcount[b * CTR_PAD], (u32)__popcll(m));
            wbase = (u32)__shfl((int)wbase, leader, 64);
            if (f) {
                u32 pos = wbase + (u32)__popcll(m & ((1ull << (u32)lane) - 1ull));
                if (pos < TOPK_CAP) {
                    float nv = fmaxf(nb[idx], 0.0f);
                    float ness = (float)exp(-(double)nv);  // correctly-rounded f32 exp
                    keysout[(u32)b * TOPK_CAP + pos] =
                        ((u64)__float_as_uint(ness) << 32) | (u32)(~idx);
                }
            }
        }
    }
}

// fused exact-rank + Taylor refine: coalesced-load + readlane-broadcast.
// Round-4 failure: "scalar" j-loads were emitted as 1024 per-wave vector
// global_loads (compiler can't prove threadIdx-derived wave id uniform,
// nor keys invariant) -> 128 exposed ~250cyc latency events -> 37 us.
// Fix: ONE coalesced load per 64-j group (lane l holds key g*64+l),
// prefetched one group ahead (hidden under ~512 cyc of compares), then
// broadcast each j-key via v_readlane with COMPILE-TIME lane index.
// Inner body/j: 2 readlane + v_cmp_gt_u64 (sgpr-pair vs vgpr-pair) +
// addc = ~4 VALU inst, no LDS, no SALU round-trip. 16 loads/wave total.
// Two accumulators break the addc serial chain.
// j split over 4 waves (1024 each); keys at j >= cnt masked to 0 at load
// (0 > k is always false -> contribute 0, bit-identical to clipping).
// rank[i] = #{j : key_j > key_i}; pad own-keys get rank >= cnt >= NK.
__global__ __launch_bounds__(256, 1) void rankref_k(const float* __restrict__ neur,
                                                    const float* __restrict__ score,
                                                    const u64* __restrict__ keys,
                                                    const u32* __restrict__ tcount,
                                                    float* __restrict__ out) {
    __shared__ u32 part[3][64];
    int b = blockIdx.y;
    int wave = threadIdx.x >> 6;
    int lane = threadIdx.x & 63;
    u32 cnt = tcount[(u32)b * CTR_PAD];
    if (cnt > TOPK_CAP) cnt = TOPK_CAP;
    const u64* kb = keys + (u32)b * TOPK_CAP;

    // lane's own i-key (same 64 i-keys for all 4 waves of the block)
    u32 i = blockIdx.x * 64u + (u32)lane;
    u64 kown = (i < cnt) ? kb[i] : 0ull;

    // this wave's j-range: 16 groups of 64
    u32 jbase = (u32)wave * 1024u;
    const u64* kqw = kb + jbase;

    u32 r0 = 0, r1 = 0;
    u64 kv = kqw[lane];
    if (jbase + (u32)lane >= cnt) kv = 0ull;
    for (int g = 0; g < 16; ++g) {
        // prefetch next group (coalesced dwordx2), masked past cnt
        u64 kvn = 0ull;
        if (g < 15) {
            kvn = kqw[(g + 1) * 64 + lane];
            if (jbase + (u32)((g + 1) * 64 + lane) >= cnt) kvn = 0ull;
        }
        u32 vlo = (u32)kv, vhi = (u32)(kv >> 32);
        #pragma unroll
        for (int e = 0; e < 64; e += 2) {
            u32 alo = (u32)__builtin_amdgcn_readlane((int)vlo, e);
            u32 ahi = (u32)__builtin_amdgcn_readlane((int)vhi, e);
            u32 blo = (u32)__builtin_amdgcn_readlane((int)vlo, e + 1);
            u32 bhi = (u32)__builtin_amdgcn_readlane((int)vhi, e + 1);
            u64 ka = ((u64)ahi << 32) | (u64)alo;
            u64 kc = ((u64)bhi << 32) | (u64)blo;
            r0 += (ka > kown) ? 1u : 0u;
            r1 += (kc > kown) ? 1u : 0u;
        }
        kv = kvn;
    }
    u32 myrank = r0 + r1;

    if (wave) part[wave - 1][lane] = myrank;
    __syncthreads();
    if (wave) return;
    myrank += part[0][lane] + part[1][lane] + part[2][lane];

    if (i >= cnt || myrank >= NK) return;

    u32 idx = ~(u32)kown;
    if (idx >= (u32)NPIX) return;  // defensive: never true for legitimate keys
    const float* s = score + (size_t)b * NPIX;
    const float* nb = neur + (size_t)b * NPIX;
    int y = (int)(idx / W), x = (int)(idx % W);
    int yc = min(max(y, 1), H - 2), xc = min(max(x, 1), W - 2);
    int p = yc * W + xc;
    float s00 = s[p], sp0 = s[p + W], sm0 = s[p - W], s0p = s[p + 1], s0m = s[p - 1];
    float spp = s[p + W + 1], spm = s[p + W - 1], smp = s[p - W + 1], smm = s[p - W - 1];
    float gy = 0.5f * (sp0 - sm0);
    float gx = 0.5f * (s0p - s0m);
    float hyy = sp0 - 2.0f * s00 + sm0;
    float hxx = s0p - 2.0f * s00 + s0m;
    float hxy = 0.25f * (spp - spm - smp + smm);
    float det = hyy * hxx - hxy * hxy;
    bool sing = fabsf(det) > 1e-12f;
    float sd = sing ? det : 1.0f;
    float iy = -(hxx * gy - hxy * gx) / sd;
    float ix = -(hyy * gx - hxy * gy) / sd;
    if (!sing) { iy = 0.0f; ix = 0.0f; }
    iy = fminf(fmaxf(iy, -0.5f), 0.5f);
    ix = fminf(fmaxf(ix, -0.5f), 0.5f);
    size_t o = ((size_t)b * NK + (size_t)myrank) * 3;
    out[o] = (float)y + 0.5f + iy;
    out[o + 1] = (float)x + 0.5f + ix;
    out[o + 2] = fmaxf(nb[idx], 0.0f);
}

extern "C" void kernel_launch(void* const* d_in, const int* in_sizes, int n_in,
                              void* d_out, int out_size, void* d_ws, size_t ws_size,
                              hipStream_t stream) {
    const float* neur = (const float*)d_in[0];
    const float* score = (const float*)d_in[1];
    float* out = (float*)d_out;
    char* ws = (char*)d_ws;
    u32* tcount = (u32*)(ws + OFF_TCOUNT);
    u32* hist = (u32*)(ws + OFF_HIST);
    u32* segcnt = (u32*)(ws + OFF_SEGCNT);
    u64* keysbuf = (u64*)(ws + OFF_KEYS);
    u32* candp = (u32*)(ws + OFF_CAND);

    size_t avail = ws_size > OFF_CAND ? ws_size - OFF_CAND : 0;
    long long cap_ll = (long long)(avail / (4ull * B * NSEG));
    int seg_cap = cap_ll > SEG_CAP_MAX ? SEG_CAP_MAX : (int)cap_ll;

    // zero tcount/hist/segcnt in one memset node (keys masked at load, not zeroed)
    hipMemsetAsync(ws, 0, OFF_ZERO_END, stream);
    cand_k<<<dim3(NTILE, GRIDY, B), 256, 0, stream>>>(neur, score, candp, segcnt, hist, seg_cap);
    compact_k<<<dim3(NSEG, B), 256, 0, stream>>>(candp, segcnt, hist, neur, keysbuf, tcount, seg_cap);
    rankref_k<<<dim3(TOPK_CAP / 64, B), 256, 0, stream>>>(neur, score, keysbuf, tcount, out);
}

// Round 6
// 173.630 us; speedup vs baseline: 1.5404x; 1.0046x over previous
//
#include <hip/hip_runtime.h>
#include <math.h>

typedef unsigned int u32;
typedef unsigned long long u64;
typedef int v16i __attribute__((ext_vector_type(16)));

#define B 8
#define H 1024
#define W 1536
#define NPIX (H * W)
#define NK 2048
#define BORDER 16
#define NSEG 64
#define TY 8
#define NTILE 6            // W / 256
#define GRIDY 31           // 992 rows / (TY * 4 waves)
#define HBINS 512
#define TOPK_CAP 4096
#define SEG_CAP_MAX 4096
#define CTR_PAD 32
#define IDX_MASK 0x1FFFFFu

// workspace layout (bytes) — [0, OFF_ZERO_END) is zeroed by one memset.
// keys IS pre-zeroed again (costs +256 KB on a 6.6 TB/s fill = ~0.04 us):
// rankref_k's scalar-pipe loads then need NO masking instructions at all.
#define OFF_TCOUNT 128      // u32[B*CTR_PAD]            ends 1152
#define OFF_HIST   4096     // u32[B*HBINS]              ends 20480
#define OFF_SEGCNT 20480    // u32[B*NSEG*CTR_PAD]       ends 86016
#define OFF_KEYS   86016    // u64[B*TOPK_CAP]           ends 348160
#define OFF_ZERO_END 348160
#define OFF_CAND   348160   // u32[B*NSEG*seg_cap]

__global__ __launch_bounds__(256) void cand_k(const float* __restrict__ neur,
                                              const float* __restrict__ score,
                                              u32* __restrict__ candp,
                                              u32* __restrict__ segcnt,
                                              u32* __restrict__ hist, int seg_cap) {
    __shared__ u32 lh[HBINS];
    int tile = blockIdx.x;
    int b = blockIdx.z;
    int wave = threadIdx.x >> 6;
    int lane = threadIdx.x & 63;
    for (int i = threadIdx.x; i < HBINS; i += 256) lh[i] = 0;
    __syncthreads();

    int strip = blockIdx.y * 4 + wave;
    int y0 = BORDER + strip * TY;
    int x0 = tile * 256 + lane * 4;
    const float* s = score + (size_t)b * NPIX;
    const float* nb = neur + (size_t)b * NPIX;
    bool haveL = (tile > 0) && (lane == 0);
    bool haveR = (tile < NTILE - 1) && (lane == 63);

    // preload: 10 score rows + 8 neur rows, all independent (one vmcnt burst)
    float4 rv[TY + 2];
    float4 nvv[TY];
    float le[TY + 2], re[TY + 2];
    const float* base_row = s + (size_t)(y0 - 1) * W + x0;
    const float* nrow = nb + (size_t)y0 * W + x0;
    #pragma unroll
    for (int r = 0; r < TY + 2; ++r) rv[r] = *(const float4*)(base_row + (size_t)r * W);
    #pragma unroll
    for (int r = 0; r < TY; ++r) nvv[r] = *(const float4*)(nrow + (size_t)r * W);
    #pragma unroll
    for (int r = 0; r < TY + 2; ++r) {
        le[r] = haveL ? base_row[(size_t)r * W - 1] : 0.0f;
        re[r] = haveR ? base_row[(size_t)r * W + 4] : 0.0f;
    }

    bool xok[4];
    #pragma unroll
    for (int e = 0; e < 4; ++e) {
        int x = x0 + e;
        xok[e] = (x >= BORDER) && (x < W - BORDER);
    }

    // phase A: pure register compute of all ext bits
    u32 extbits = 0;
    {
        float4 hm, h0, hp;
        #pragma unroll
        for (int r = 0; r < 2; ++r) {
            float4 c = rv[r];
            float l = __shfl_up(c.w, 1); if (haveL) l = le[r];
            float rr = __shfl_down(c.x, 1); if (haveR) rr = re[r];
            float4 hh;
            hh.x = fmaxf(fmaxf(l, c.x), c.y);
            hh.y = fmaxf(fmaxf(c.x, c.y), c.z);
            hh.z = fmaxf(fmaxf(c.y, c.z), c.w);
            hh.w = fmaxf(fmaxf(c.z, c.w), rr);
            if (r == 0) hm = hh; else h0 = hh;
        }
        #pragma unroll
        for (int ys = 0; ys < TY; ++ys) {
            float4 c = rv[ys + 2];
            float l = __shfl_up(c.w, 1); if (haveL) l = le[ys + 2];
            float rr = __shfl_down(c.x, 1); if (haveR) rr = re[ys + 2];
            hp.x = fmaxf(fmaxf(l, c.x), c.y);
            hp.y = fmaxf(fmaxf(c.x, c.y), c.z);
            hp.z = fmaxf(fmaxf(c.y, c.z), c.w);
            hp.w = fmaxf(fmaxf(c.z, c.w), rr);
            float pv[4];
            pv[0] = fmaxf(fmaxf(hm.x, h0.x), hp.x);
            pv[1] = fmaxf(fmaxf(hm.y, h0.y), hp.y);
            pv[2] = fmaxf(fmaxf(hm.z, h0.z), hp.z);
            pv[3] = fmaxf(fmaxf(hm.w, h0.w), hp.w);
            float4 c0 = rv[ys + 1];
            float cv[4] = {c0.x, c0.y, c0.z, c0.w};
            #pragma unroll
            for (int e = 0; e < 4; ++e)
                if (xok[e] && cv[e] >= pv[e]) extbits |= (1u << (ys * 4 + e));
            hm = h0; h0 = hp;
        }
    }

    // phase B: one wave scan + one leader atomic; nv already in registers
    u32 c = (u32)__popc(extbits);
    u32 scan = c;
    #pragma unroll
    for (int off = 1; off < 64; off <<= 1) {
        u32 o = (u32)__shfl_up((int)scan, off, 64);
        if (lane >= off) scan += o;
    }
    u32 excl = scan - c;
    u32 tot = (u32)__shfl((int)scan, 63, 64);
    if (tot) {
        int seg = (strip * NTILE + tile) & (NSEG - 1);
        u32* ctr = &segcnt[(u32)(b * NSEG + seg) * CTR_PAD];
        u32 base = 0;
        if (lane == 63) base = atomicAdd(ctr, scan);
        base = (u32)__shfl((int)base, 63, 64);
        u32 pos0 = base + excl;
        u32 sbase = (u32)(b * NSEG + seg) * (u32)seg_cap;
        u32 idxbase = (u32)(y0 * W + x0);
        #pragma unroll
        for (int k = 0; k < 32; ++k) {
            if (extbits & (1u << k)) {
                const int ro = k >> 2, e = k & 3;
                float4 nq = nvv[ro];
                float raw = (e == 0) ? nq.x : (e == 1) ? nq.y : (e == 2) ? nq.z : nq.w;
                float nv = fmaxf(raw, 0.0f);
                u32 fb = __float_as_uint(nv);
                u32 bin = fb >> 21; if (bin > HBINS - 1) bin = HBINS - 1;
                atomicAdd(&lh[bin], 1u);
                u32 idx = idxbase + (u32)ro * W + (u32)e;
                u32 p = pos0 + (u32)__popc(extbits & ((1u << k) - 1u));
                if ((int)p < seg_cap) candp[sbase + p] = (bin << 21) | idx;
            }
        }
    }
    __syncthreads();
    for (int i = threadIdx.x; i < HBINS; i += 256) {
        u32 v = lh[i];
        if (v) atomicAdd(&hist[(u32)b * HBINS + i], v);
    }
}

__global__ __launch_bounds__(256) void compact_k(const u32* __restrict__ candp,
                                                 const u32* __restrict__ segcnt,
                                                 const u32* __restrict__ hist,
                                                 const float* __restrict__ neur,
                                                 u64* __restrict__ keysout,
                                                 u32* tcount, int seg_cap) {
    __shared__ u32 piv_s;
    int seg = blockIdx.x;
    int b = blockIdx.y;
    int lane = threadIdx.x & 63;
    // wave 0: recompute pivot from hist (512 bins, 8/lane + shfl scan)
    if (threadIdx.x < 64) {
        if (threadIdx.x == 0) piv_s = 0xFFFFFFFFu;
        u32 v[8];
        u32 s8 = 0;
        #pragma unroll
        for (int e = 0; e < 8; ++e) {
            v[e] = hist[(u32)b * HBINS + (u32)threadIdx.x * 8u + e];
            s8 += v[e];
        }
        u32 incl = s8;
        #pragma unroll
        for (int off = 1; off < 64; off <<= 1) {
            u32 o = (u32)__shfl_up((int)incl, off, 64);
            if (lane >= off) incl += o;
        }
        u32 excl = incl - s8;
        if (excl < NK && incl >= NK) {
            u32 cum = excl;
            u32 T = 0;
            #pragma unroll
            for (int e = 0; e < 8; ++e) {
                cum += v[e];
                if (cum >= NK) { T = (u32)threadIdx.x * 8u + e; break; }
            }
            piv_s = (T + 2u) << 21;  // include bins <= T+1 entirely
        }
    }
    __syncthreads();
    u32 piv = piv_s;
    const float* nb = neur + (size_t)b * NPIX;

    u32 cnt = segcnt[(u32)(b * NSEG + seg) * CTR_PAD];
    if ((int)cnt > seg_cap) cnt = (u32)seg_cap;
    u32 base = (u32)(b * NSEG + seg) * (u32)seg_cap;
    u32 iters = (cnt + 255u) / 256u;
    for (u32 it = 0; it < iters; ++it) {
        u32 i = it * 256u + threadIdx.x;
        bool f = false;
        u32 idx = 0;
        if (i < cnt) {
            u32 p = candp[base + i];
            f = (p < piv);
            idx = p & IDX_MASK;
        }
        u64 m = __ballot((int)f);
        if (m) {
            int leader = __ffsll((long long)m) - 1;
            u32 wbase = 0;
            if (lane == leader) wbase = atomicAdd(&tcount[b * CTR_PAD], (u32)__popcll(m));
            wbase = (u32)__shfl((int)wbase, leader, 64);
            if (f) {
                u32 pos = wbase + (u32)__popcll(m & ((1ull << (u32)lane) - 1ull));
                if (pos < TOPK_CAP) {
                    float nv = fmaxf(nb[idx], 0.0f);
                    float ness = (float)exp(-(double)nv);  // correctly-rounded f32 exp
                    keysout[(u32)b * TOPK_CAP + pos] =
                        ((u64)__float_as_uint(ness) << 32) | (u32)(~idx);
                }
            }
        }
    }
}

// fused exact-rank + Taylor refine, scalar-memory-broadcast form.
// Round-5 analysis: readlane form is VALU-ISSUE-bound (~6 inst/j: 2
// readlane + pair-assemble + cmp + addc, plus SGPR-read hazard stalls)
// -> 25 us. Fix: feed j-keys through the SCALAR pipe. Keys tail is
// pre-zeroed by the memset, so no masking anywhere; the per-wave key
// pointer is made uniform via readfirstlane; 8 keys come in per
// s_load_dwordx16 with the lgkmcnt(0) wait FUSED INSIDE the same asm
// (output data-dependence -> uses can't be hoisted above the wait
// [rule #18]; SMEM completes out-of-order so wait-0 per group is the
// only safe discipline). Inner body per j: v_cmp_gt_u64 (sgpr-pair vs
// vgpr-pair) + addc = 2 VALU inst; 4 rotating accumulators break the
// vcc chain; u64 assembly from adjacent SGPRs is free scalar work.
// 8 waves/block (512 j = 64 groups each): 4096 waves = 4/SIMD hides
// the per-group scalar-load latency via TLP.
// rank[i] = #{j : key_j > key_i}; keys distinct; valid keys > 0; pad
// zeros contribute 0 under strict >, pad own-keys get rank >= cnt >= NK
// and are also cut by i >= cnt -> never output. Bit-identical ordering.
__global__ __launch_bounds__(512, 1) void rankref_k(const float* __restrict__ neur,
                                                    const float* __restrict__ score,
                                                    const u64* __restrict__ keys,
                                                    const u32* __restrict__ tcount,
                                                    float* __restrict__ out) {
    __shared__ u32 part[7][64];
    int b = blockIdx.y;
    int wave = threadIdx.x >> 6;
    int lane = threadIdx.x & 63;
    u32 cnt = tcount[(u32)b * CTR_PAD];
    if (cnt > TOPK_CAP) cnt = TOPK_CAP;
    const u64* kb = keys + (u32)b * TOPK_CAP;

    // lane's own i-key (same 64 i-keys for all 8 waves of the block);
    // always in-bounds, tail is zero-padded
    u32 i = blockIdx.x * 64u + (u32)lane;
    u64 kown = kb[i];

    // this wave's j-range: 512 j = 64 groups of 8 keys; pointer made
    // uniform so the asm "s" constraint is legal
    u32 jbase = (u32)wave * 512u;
    uintptr_t p = (uintptr_t)(kb + jbase);
    u32 plo = (u32)__builtin_amdgcn_readfirstlane((int)(u32)p);
    u32 phi = (u32)__builtin_amdgcn_readfirstlane((int)(u32)(p >> 32));
    const u64* kqu = (const u64*)(((uintptr_t)phi << 32) | (uintptr_t)plo);

    u32 r0 = 0, r1 = 0, r2 = 0, r3 = 0;
    #pragma unroll 2
    for (int g = 0; g < 64; ++g) {
        v16i kk;
        asm volatile("s_load_dwordx16 %0, %1, 0x0\n\ts_waitcnt lgkmcnt(0)"
                     : "=s"(kk)
                     : "s"(kqu + (size_t)g * 8)
                     : "memory");
        u64 k0 = ((u64)(u32)kk[1]  << 32) | (u64)(u32)kk[0];
        u64 k1 = ((u64)(u32)kk[3]  << 32) | (u64)(u32)kk[2];
        u64 k2 = ((u64)(u32)kk[5]  << 32) | (u64)(u32)kk[4];
        u64 k3 = ((u64)(u32)kk[7]  << 32) | (u64)(u32)kk[6];
        u64 k4 = ((u64)(u32)kk[9]  << 32) | (u64)(u32)kk[8];
        u64 k5 = ((u64)(u32)kk[11] << 32) | (u64)(u32)kk[10];
        u64 k6 = ((u64)(u32)kk[13] << 32) | (u64)(u32)kk[12];
        u64 k7 = ((u64)(u32)kk[15] << 32) | (u64)(u32)kk[14];
        r0 += (k0 > kown) ? 1u : 0u;
        r1 += (k1 > kown) ? 1u : 0u;
        r2 += (k2 > kown) ? 1u : 0u;
        r3 += (k3 > kown) ? 1u : 0u;
        r0 += (k4 > kown) ? 1u : 0u;
        r1 += (k5 > kown) ? 1u : 0u;
        r2 += (k6 > kown) ? 1u : 0u;
        r3 += (k7 > kown) ? 1u : 0u;
    }
    u32 myrank = (r0 + r1) + (r2 + r3);

    if (wave) part[wave - 1][lane] = myrank;
    __syncthreads();
    if (wave) return;
    #pragma unroll
    for (int wv = 0; wv < 7; ++wv) myrank += part[wv][lane];

    if (i >= cnt || myrank >= NK) return;

    u32 idx = ~(u32)kown;
    if (idx >= (u32)NPIX) return;  // defensive: never true for legitimate keys
    const float* s = score + (size_t)b * NPIX;
    const float* nb = neur + (size_t)b * NPIX;
    int y = (int)(idx / W), x = (int)(idx % W);
    int yc = min(max(y, 1), H - 2), xc = min(max(x, 1), W - 2);
    int pp = yc * W + xc;
    float s00 = s[pp], sp0 = s[pp + W], sm0 = s[pp - W], s0p = s[pp + 1], s0m = s[pp - 1];
    float spp = s[pp + W + 1], spm = s[pp + W - 1], smp = s[pp - W + 1], smm = s[pp - W - 1];
    float gy = 0.5f * (sp0 - sm0);
    float gx = 0.5f * (s0p - s0m);
    float hyy = sp0 - 2.0f * s00 + sm0;
    float hxx = s0p - 2.0f * s00 + s0m;
    float hxy = 0.25f * (spp - spm - smp + smm);
    float det = hyy * hxx - hxy * hxy;
    bool sing = fabsf(det) > 1e-12f;
    float sd = sing ? det : 1.0f;
    float iy = -(hxx * gy - hxy * gx) / sd;
    float ix = -(hyy * gx - hxy * gy) / sd;
    if (!sing) { iy = 0.0f; ix = 0.0f; }
    iy = fminf(fmaxf(iy, -0.5f), 0.5f);
    ix = fminf(fmaxf(ix, -0.5f), 0.5f);
    size_t o = ((size_t)b * NK + (size_t)myrank) * 3;
    out[o] = (float)y + 0.5f + iy;
    out[o + 1] = (float)x + 0.5f + ix;
    out[o + 2] = fmaxf(nb[idx], 0.0f);
}

extern "C" void kernel_launch(void* const* d_in, const int* in_sizes, int n_in,
                              void* d_out, int out_size, void* d_ws, size_t ws_size,
                              hipStream_t stream) {
    const float* neur = (const float*)d_in[0];
    const float* score = (const float*)d_in[1];
    float* out = (float*)d_out;
    char* ws = (char*)d_ws;
    u32* tcount = (u32*)(ws + OFF_TCOUNT);
    u32* hist = (u32*)(ws + OFF_HIST);
    u32* segcnt = (u32*)(ws + OFF_SEGCNT);
    u64* keysbuf = (u64*)(ws + OFF_KEYS);
    u32* candp = (u32*)(ws + OFF_CAND);

    size_t avail = ws_size > OFF_CAND ? ws_size - OFF_CAND : 0;
    long long cap_ll = (long long)(avail / (4ull * B * NSEG));
    int seg_cap = cap_ll > SEG_CAP_MAX ? SEG_CAP_MAX : (int)cap_ll;

    // zero tcount/hist/segcnt/keys in one memset node
    hipMemsetAsync(ws, 0, OFF_ZERO_END, stream);
    cand_k<<<dim3(NTILE, GRIDY, B), 256, 0, stream>>>(neur, score, candp, segcnt, hist, seg_cap);
    compact_k<<<dim3(NSEG, B), 256, 0, stream>>>(candp, segcnt, hist, neur, keysbuf, tcount, seg_cap);
    rankref_k<<<dim3(TOPK_CAP / 64, B), 512, 0, stream>>>(neur, score, keysbuf, tcount, out);
}